// Round 2
// baseline (108.802 us; speedup 1.0000x reference)
//
#include <hip/hip_runtime.h>

// LIF recurrence: v = 0.25*v + 0.75*x_t ; s = (v > 1.0f) ; v -= s   (vth=1, reset=0)
// B=64, T=256, U=1024 fp32. Sequential over T => parallelism fixed at B*U chains.
//
// R2 theory: kernel proper ~40us vs 21.3us BW roofline (134MB @ 6.3TB/s; harness
// fills prove 6.3 achievable). Little's law: 16KB/CU in flight at ~1.3us loaded
// latency = 3.2TB/s (matches). Fix: 2 neurons/thread (8B/lane => 512B/wave-load,
// half the instrs) + depth-3 buffer rotation (prefetch 2 chunks ahead, no reg
// copy) => 32 outstanding 8B loads/wave = 32KB/CU in flight, 2 waves/CU.
// Outstanding vmem/wave = 32 loads + 16 stores = 48 < vmcnt cap 63.
//
// R3: compile fix only — __builtin_nontemporal_store rejects HIP_vector_type;
// use clang ext_vector_type(2) (same dwordx2 codegen, builtin-compatible).
//
// Bit-exactness vs reference: non-fused __fmul_rn/__fadd_rn so the spike
// compare (v > 1.0f) sees identical rounding; v -= s is exact.

typedef float f32x2 __attribute__((ext_vector_type(2)));

constexpr int kB  = 64;
constexpr int kT  = 256;
constexpr int kU  = 1024;
constexpr int kU2 = kU / 2;      // f32x2 columns = 512
constexpr int kC  = 16;          // chunk length (t-steps per chunk)
constexpr int kNCH = kT / kC;    // 16 chunks

__global__ __launch_bounds__(128)
void lif_kernel(const float* __restrict__ x, float* __restrict__ out) {
    const int idx = blockIdx.x * blockDim.x + threadIdx.x;   // over B*U/2 = 32768
    const int b   = idx >> 9;             // / kU2
    const int u2  = idx & (kU2 - 1);      // % kU2

    const size_t base2 = (size_t)b * kT * kU2 + u2;          // in f32x2 units
    const f32x2* __restrict__ xp = reinterpret_cast<const f32x2*>(x) + base2;
    f32x2* __restrict__ op       = reinterpret_cast<f32x2*>(out) + base2;

    // 3-deep rotating chunk buffers; all indices compile-time after unroll
    // (rule: runtime-indexed arrays go to scratch — every access below is
    // constant-folded by the full unroll).
    f32x2 buf[3][kC];

    // prologue: issue loads for chunks 0 and 1 (32 loads in flight)
#pragma unroll
    for (int j = 0; j < kC; ++j)
        buf[0][j] = xp[(size_t)j * kU2];
#pragma unroll
    for (int j = 0; j < kC; ++j)
        buf[1][j] = xp[(size_t)(kC + j) * kU2];

    float v0 = 0.0f, v1 = 0.0f;

#pragma unroll
    for (int c = 0; c < kNCH; ++c) {
        // issue chunk c+2's loads first — independent of the v-chain, lands
        // while we compute chunks c and c+1 (~2 iterations of cover).
        if (c + 2 < kNCH) {
#pragma unroll
            for (int j = 0; j < kC; ++j)
                buf[(c + 2) % 3][j] = xp[(size_t)((c + 2) * kC + j) * kU2];
        }
        // compute + store chunk c (data arrived 2 iterations ago)
#pragma unroll
        for (int j = 0; j < kC; ++j) {
            const f32x2 xx = buf[c % 3][j];

            const float a0 = __fmul_rn(0.25f, v0);
            const float m0 = __fmul_rn(0.75f, xx.x);
            v0 = __fadd_rn(a0, m0);
            const float s0 = (v0 > 1.0f) ? 1.0f : 0.0f;
            v0 = __fsub_rn(v0, s0);

            const float a1 = __fmul_rn(0.25f, v1);
            const float m1 = __fmul_rn(0.75f, xx.y);
            v1 = __fadd_rn(a1, m1);
            const float s1 = (v1 > 1.0f) ? 1.0f : 0.0f;
            v1 = __fsub_rn(v1, s1);

            f32x2 s;
            s.x = s0;
            s.y = s1;
            __builtin_nontemporal_store(s, &op[(size_t)(c * kC + j) * kU2]);
        }
    }
}

extern "C" void kernel_launch(void* const* d_in, const int* in_sizes, int n_in,
                              void* d_out, int out_size, void* d_ws, size_t ws_size,
                              hipStream_t stream) {
    const float* x = (const float*)d_in[0];
    float* out = (float*)d_out;

    const int nthreads = kB * kU2;         // 32768 f32x2 chains
    const int block = 128;                 // 2 waves/block
    const int grid = nthreads / block;     // 256 blocks -> 1 block/CU, 2 waves/CU
    lif_kernel<<<grid, block, 0, stream>>>(x, out);
}

// Round 3
// 107.768 us; speedup vs baseline: 1.0096x; 1.0096x over previous
//
#include <hip/hip_runtime.h>

// LIF recurrence: v = 0.25*v + 0.75*x_t ; s = (v > 1.0f) ; v -= s   (vth=1, reset=0)
// B=64, T=256, U=1024 fp32.
//
// R4: T-SPLIT. Parallelism was capped at B*U chains = 2 waves/CU (f32x2) ->
// latency-bound at ~3.1 TB/s (R3 post-mortem: peak in-flight bytes/wave didn't
// matter; too few waves to cover issue/drain phases). The LIF scan is
// exponentially self-forgetting: state differences contract 4x/step (0.25*v),
// hitting bit-exact equality after ~14 clean steps; spike-flip cascades during
// warmup die geometrically (P(survive 64 steps) ~ 1e-13/chain). So split T:
//   seg0: t in [0,128) exact from v=0.
//   seg1: warmup t in [64,128) from v=0 (not stored), then store t in [128,256).
// => 2x waves (4/CU), +25% read traffic (151 MB total, 24 us BW floor).
// Depth-3 rotating chunk pipeline per wave (32 outstanding 8B loads) retained.
//
// Bit-exactness: identical non-fused __fmul_rn/__fadd_rn/__fsub_rn sequence as
// reference; seg1 boundary state is bit-exact w.h.p. ~1-1e-8 (see above).

typedef float f32x2 __attribute__((ext_vector_type(2)));

constexpr int kB   = 64;
constexpr int kT   = 256;
constexpr int kU   = 1024;
constexpr int kU2  = kU / 2;     // f32x2 columns = 512
constexpr int kSeg = 128;        // stored steps per segment
constexpr int kWarm = 64;        // warmup steps for seg1
constexpr int kC   = 16;         // chunk length (t-steps per chunk)

template <int NWARM>
__device__ __forceinline__ void run_chain(const f32x2* __restrict__ lp,
                                          f32x2* __restrict__ op) {
    constexpr int NSTEPS = NWARM + kSeg;     // 128 or 192
    constexpr int NCH    = NSTEPS / kC;      // 8 or 12

    // 3-deep rotating chunk buffers; fully unrolled -> all indices static
    // (runtime-indexed ext_vector arrays would go to scratch).
    f32x2 buf[3][kC];

    // prologue: chunks 0 and 1 in flight (32 loads)
#pragma unroll
    for (int j = 0; j < kC; ++j)
        buf[0][j] = lp[(size_t)j * kU2];
#pragma unroll
    for (int j = 0; j < kC; ++j)
        buf[1][j] = lp[(size_t)(kC + j) * kU2];

    float v0 = 0.0f, v1 = 0.0f;

#pragma unroll
    for (int c = 0; c < NCH; ++c) {
        if (c + 2 < NCH) {
#pragma unroll
            for (int j = 0; j < kC; ++j)
                buf[(c + 2) % 3][j] = lp[(size_t)((c + 2) * kC + j) * kU2];
        }
#pragma unroll
        for (int j = 0; j < kC; ++j) {
            const f32x2 xx = buf[c % 3][j];

            const float a0 = __fmul_rn(0.25f, v0);
            const float m0 = __fmul_rn(0.75f, xx.x);
            v0 = __fadd_rn(a0, m0);
            const float s0 = (v0 > 1.0f) ? 1.0f : 0.0f;
            v0 = __fsub_rn(v0, s0);

            const float a1 = __fmul_rn(0.25f, v1);
            const float m1 = __fmul_rn(0.75f, xx.y);
            v1 = __fadd_rn(a1, m1);
            const float s1 = (v1 > 1.0f) ? 1.0f : 0.0f;
            v1 = __fsub_rn(v1, s1);

            const int t = c * kC + j;
            if (t >= NWARM) {                 // compile-time per unrolled step
                f32x2 s;
                s.x = s0;
                s.y = s1;
                __builtin_nontemporal_store(s, op + (size_t)(t - NWARM) * kU2);
            }
        }
    }
}

__global__ __launch_bounds__(64)
void lif_kernel(const float* __restrict__ x, float* __restrict__ out) {
    const int bid = blockIdx.x;
    const int seg = bid >> 9;                          // blocks 0..511 seg0, 512..1023 seg1
    const int idx = ((bid & 511) << 6) | threadIdx.x;  // 0..32767 f32x2 chains
    const int b   = idx >> 9;                          // / kU2
    const int u2  = idx & (kU2 - 1);                   // % kU2

    const size_t base2 = (size_t)b * kT * kU2 + u2;    // in f32x2 units
    const f32x2* __restrict__ xp = reinterpret_cast<const f32x2*>(x) + base2;
    f32x2* __restrict__ op       = reinterpret_cast<f32x2*>(out) + base2;

    if (seg == 0) {
        run_chain<0>(xp, op);
    } else {
        run_chain<kWarm>(xp + (size_t)(kSeg - kWarm) * kU2,   // loads start at t=64
                         op + (size_t)kSeg * kU2);            // stores start at t=128
    }
}

extern "C" void kernel_launch(void* const* d_in, const int* in_sizes, int n_in,
                              void* d_out, int out_size, void* d_ws, size_t ws_size,
                              hipStream_t stream) {
    const float* x = (const float*)d_in[0];
    float* out = (float*)d_out;

    // 1024 blocks x 64 threads = 2 segments x 32768 chains; 4 blocks/CU ->
    // 4 waves/CU, mixed seg0/seg1 for per-CU load balance.
    lif_kernel<<<1024, 64, 0, stream>>>(x, out);
}

// Round 4
// 106.992 us; speedup vs baseline: 1.0169x; 1.0073x over previous
//
#include <hip/hip_runtime.h>

// LIF recurrence: v = 0.25*v + 0.75*x_t ; s = (v > 1.0f) ; v -= s   (vth=1, reset=0)
// B=64, T=256, U=1024 fp32.
//
// R5: 4-WAY T-SPLIT (discriminating experiment). R3/R4 post-mortem: dur_us is
// pinned at 107+-1 across three structurally different kernels, top-5 rocprof
// rows are all ~43us 256MiB harness fills -> hypothesis: dur_us ~= 2 fills (86us)
// + kernel (~21us, already near HBM roofline 134MB/6.3TB/s). Counter-hypothesis:
// ~61us fixed + ~46us latency-bound kernel. Both are attacked by max concurrency:
// 4 T-segments x 32768 f32x2 chains = 2048 blocks x 64thr = 8 waves/CU, depth-3
// pipeline (32 outstanding 8B loads/wave) = 128KB/CU in flight. Warmup re-reads
// (24MiB) are LLC-hits (input 64MiB << 256MiB IC), HBM traffic unchanged 134MB.
// In+out (128MiB) both LLC-fit -> true floor may be LLC-BW (~10us), not HBM.
//
// Correctness of the split: state diff contracts 4x/step (0.25*v); bit-exact
// equality after ~14 clean steps. Failure needs the last warmup spike-flip at
// step >=21 of 32: P ~ 1e-10/chain x 98k chains ~ 1e-5. R3 (warmup 64) passed
// absmax=0.0 on the real data.
//
// Bit-exactness: identical non-fused __fmul_rn/__fadd_rn/__fsub_rn sequence as
// reference so the spike compare (v > 1.0f) sees identical rounding.

typedef float f32x2 __attribute__((ext_vector_type(2)));

constexpr int kB    = 64;
constexpr int kT    = 256;
constexpr int kU    = 1024;
constexpr int kU2   = kU / 2;      // f32x2 columns = 512
constexpr int kNSEG = 4;
constexpr int kStore = kT / kNSEG; // 64 stored steps per segment
constexpr int kWarm  = 32;         // warmup steps for segs 1..3
constexpr int kC     = 16;         // chunk length (t-steps per chunk)

template <int NWARM, int NSTORE>
__device__ __forceinline__ void run_chain(const f32x2* __restrict__ lp,
                                          f32x2* __restrict__ op) {
    constexpr int NSTEPS = NWARM + NSTORE;   // 64 or 96
    constexpr int NCH    = NSTEPS / kC;      // 4 or 6

    // 3-deep rotating chunk buffers; fully unrolled -> all indices static
    // (runtime-indexed ext_vector arrays go to scratch).
    f32x2 buf[3][kC];

    // prologue: chunks 0 and 1 in flight (32 loads)
#pragma unroll
    for (int j = 0; j < kC; ++j)
        buf[0][j] = lp[(size_t)j * kU2];
#pragma unroll
    for (int j = 0; j < kC; ++j)
        buf[1][j] = lp[(size_t)(kC + j) * kU2];

    float v0 = 0.0f, v1 = 0.0f;

#pragma unroll
    for (int c = 0; c < NCH; ++c) {
        if (c + 2 < NCH) {
#pragma unroll
            for (int j = 0; j < kC; ++j)
                buf[(c + 2) % 3][j] = lp[(size_t)((c + 2) * kC + j) * kU2];
        }
#pragma unroll
        for (int j = 0; j < kC; ++j) {
            const f32x2 xx = buf[c % 3][j];

            const float a0 = __fmul_rn(0.25f, v0);
            const float m0 = __fmul_rn(0.75f, xx.x);
            v0 = __fadd_rn(a0, m0);
            const float s0 = (v0 > 1.0f) ? 1.0f : 0.0f;
            v0 = __fsub_rn(v0, s0);

            const float a1 = __fmul_rn(0.25f, v1);
            const float m1 = __fmul_rn(0.75f, xx.y);
            v1 = __fadd_rn(a1, m1);
            const float s1 = (v1 > 1.0f) ? 1.0f : 0.0f;
            v1 = __fsub_rn(v1, s1);

            const int t = c * kC + j;
            if (t >= NWARM) {                 // compile-time per unrolled step
                f32x2 s;
                s.x = s0;
                s.y = s1;
                __builtin_nontemporal_store(s, op + (size_t)(t - NWARM) * kU2);
            }
        }
    }
}

__global__ __launch_bounds__(64)
void lif_kernel(const float* __restrict__ x, float* __restrict__ out) {
    const int bid = blockIdx.x;
    const int seg = bid >> 9;                          // 0..3
    const int idx = ((bid & 511) << 6) | threadIdx.x;  // 0..32767 f32x2 chains
    const int b   = idx >> 9;                          // / kU2
    const int u2  = idx & (kU2 - 1);                   // % kU2

    const size_t base2 = (size_t)b * kT * kU2 + u2;    // in f32x2 units
    const f32x2* __restrict__ xp = reinterpret_cast<const f32x2*>(x) + base2;
    f32x2* __restrict__ op       = reinterpret_cast<f32x2*>(out) + base2;

    if (seg == 0) {
        run_chain<0, kStore>(xp, op);
    } else {
        const int t_store = seg * kStore;              // first stored step
        const int t_load  = t_store - kWarm;           // warmup load start
        run_chain<kWarm, kStore>(xp + (size_t)t_load * kU2,
                                 op + (size_t)t_store * kU2);
    }
}

extern "C" void kernel_launch(void* const* d_in, const int* in_sizes, int n_in,
                              void* d_out, int out_size, void* d_ws, size_t ws_size,
                              hipStream_t stream) {
    const float* x = (const float*)d_in[0];
    float* out = (float*)d_out;

    // 2048 blocks x 64 threads = 4 segments x 32768 chains; 8 blocks/CU ->
    // 8 waves/CU; each CU gets a balanced mix of short (seg0) and long waves.
    lif_kernel<<<2048, 64, 0, stream>>>(x, out);
}